// Round 5
// baseline (382.301 us; speedup 1.0000x reference)
//
#include <hip/hip_runtime.h>
#include <hip/hip_bf16.h>

#define N_NODES 100000
#define N_EDGES 1600000
#define DIM 64

#define SCAN_BLOCK 1024
#define NSB2 ((N_NODES + SCAN_BLOCK - 1) / SCAN_BLOCK)   // 98 scan blocks
#define PACKB4 ((N_NODES * DIM / 4 + 255) / 256)         // 6250 (exact)
#define HISTB ((N_EDGES / 4 + 255) / 256)                // 1563
#define NPW 8                                            // nodes per wave (pull)
#define PULLB (N_NODES / 32)                             // 3125 blocks, 32 nodes each

typedef __attribute__((ext_vector_type(8))) short bf16x8;
typedef __attribute__((ext_vector_type(4))) float f32x4;

#if defined(__has_builtin)
#if __has_builtin(__builtin_amdgcn_fdot2_f32_bf16)
#define HAVE_DOT2 1
typedef __attribute__((ext_vector_type(2))) __bf16 bf16x2v;
#endif
#endif

// ---------------- ws layout ----------------
// At      : 32 KB bf16 (combined epilogue matrix, transposed)
// cvec    : 1 KB
// records : E * 8 B  (u64 {hi=bf16x2 coef er,ei; lo=src}); written node-grouped
//           by the atomic scatter (order within a node is arbitrary — pull sums)
// hpack   : N*DIM*4B ({bf16 hr, bf16 hi} interleaved)
// cnt     : N ints  (memset 0 -> histogram -> in-place block-local excl prefix)
// bsum/bpre : scan block sums; cursor : N ints (global excl prefix -> after
//           scatter, cursor[n] == inclusive prefix == pull's inc[])

__device__ __forceinline__ unsigned pack_bf16x2(float lo, float hi) {
  unsigned ulo = (unsigned)__hip_bfloat16_raw(__float2bfloat16(lo)).x;
  unsigned uhi = (unsigned)__hip_bfloat16_raw(__float2bfloat16(hi)).x;
  return ulo | (uhi << 16);
}
__device__ __forceinline__ float unpack_lo(unsigned u) {
  return __int_as_float((int)(u << 16));
}
__device__ __forceinline__ float unpack_hi(unsigned u) {
  return __int_as_float((int)(u & 0xFFFF0000u));
}
__device__ __forceinline__ unsigned short f2bf(float x) {
  return __hip_bfloat16_raw(__float2bfloat16(x)).x;
}

// Fused setup: pack_h (blocks 0..PACKB4-1, float4-vectorized), combined
// epilogue operator (next 64 blocks), per-node histogram via global atomics
// (last HISTB blocks; cnt[] zeroed by hipMemsetAsync before this kernel).
__global__ __launch_bounds__(256) void setup_fused_kernel(
    const float* __restrict__ h_real, const float* __restrict__ h_imag,
    unsigned* __restrict__ hpack, const float* __restrict__ W1,
    const float* __restrict__ b1, const float* __restrict__ W2,
    const float* __restrict__ b2, unsigned short* __restrict__ At,
    float* __restrict__ cvec, const int* __restrict__ dst,
    int* __restrict__ cnt) {
  const int bid = blockIdx.x;
  const int tid = threadIdx.x;
  if (bid < PACKB4) {
    const int i = bid * 256 + tid;  // covers N*DIM/4 exactly
    const float4 hr = ((const float4*)h_real)[i];
    const float4 hi = ((const float4*)h_imag)[i];
    uint4 o;
    o.x = pack_bf16x2(hr.x, hi.x);
    o.y = pack_bf16x2(hr.y, hi.y);
    o.z = pack_bf16x2(hr.z, hi.z);
    o.w = pack_bf16x2(hr.w, hi.w);
    ((uint4*)hpack)[i] = o;
    return;
  }
  if (bid < PACKB4 + 64) {
    const int idx = (bid - PACKB4) * 256 + tid;
    if (idx < 128 * 128) {
      const int n = idx >> 7, k = idx & 127;
      float v;
      if (n < 64) {
        v = (k < 64) ? W1[n * 64 + k] : -W2[n * 64 + (k - 64)];
      } else {
        const int nn = n - 64;
        if (k < 64) {
          float s = 0.0f;
          for (int j = 0; j < 64; ++j) s += W1[j * 64 + k] * W2[nn * 64 + j];
          v = s;
        } else {
          const int kk = k - 64;
          float s = 0.0f;
          for (int j = 0; j < 64; ++j) s += W2[j * 64 + kk] * W2[nn * 64 + j];
          v = W1[nn * 64 + kk] - s;
        }
      }
      At[n * 128 + k] = f2bf(v);
    }
    if (idx < 128) {
      if (idx < 64) {
        cvec[idx] = b1[idx] - b2[idx];
      } else {
        const int nn = idx - 64;
        float s = 0.0f;
        for (int j = 0; j < 64; ++j) s += (b1[j] - b2[j]) * W2[nn * 64 + j];
        cvec[idx] = s + b1[nn] + b2[nn];
      }
    }
    return;
  }
  // histogram role: 4 edges per thread, vectorized dst read
  const int hb = bid - PACKB4 - 64;
  const int e0 = (hb * 256 + tid) * 4;
  if (e0 < N_EDGES) {  // N_EDGES % 4 == 0 -> whole int4 valid
    const int4 t4 = *(const int4*)(dst + e0);
    atomicAdd(&cnt[t4.x], 1);
    atomicAdd(&cnt[t4.y], 1);
    atomicAdd(&cnt[t4.z], 1);
    atomicAdd(&cnt[t4.w], 1);
  }
}

// In-place: cnt -> BLOCK-LOCAL exclusive prefix; bsum[blk] = block total.
__global__ __launch_bounds__(SCAN_BLOCK) void scan1_kernel(
    int* __restrict__ cnt, int* __restrict__ bsum) {
  __shared__ int wsum[16];
  const int tid = threadIdx.x;
  const int lane = tid & 63;
  const int w = tid >> 6;
  const int i = blockIdx.x * SCAN_BLOCK + tid;
  const int orig = (i < N_NODES) ? cnt[i] : 0;
  int v = orig;
#pragma unroll
  for (int off = 1; off < 64; off <<= 1) {
    int t = __shfl_up(v, off);
    if (lane >= off) v += t;
  }
  if (lane == 63) wsum[w] = v;
  __syncthreads();
  if (w == 0) {
    int s = (lane < 16) ? wsum[lane] : 0;
#pragma unroll
    for (int off = 1; off < 16; off <<= 1) {
      int t = __shfl_up(s, off);
      if (lane >= off) s += t;
    }
    if (lane < 16) wsum[lane] = s;
  }
  __syncthreads();
  const int wex = (w == 0) ? 0 : wsum[w - 1];
  if (i < N_NODES) cnt[i] = wex + v - orig;  // exclusive (block-local)
  if (tid == SCAN_BLOCK - 1) bsum[blockIdx.x] = wex + v;
}

// Scan of the NSB2 block sums -> exclusive bpre.
__global__ __launch_bounds__(256) void scan2_kernel(
    const int* __restrict__ bsum, int* __restrict__ bpre) {
  __shared__ int wsum[4];
  const int tid = threadIdx.x;
  const int lane = tid & 63;
  const int w = tid >> 6;
  const int orig = (tid < NSB2) ? bsum[tid] : 0;
  int v = orig;
#pragma unroll
  for (int off = 1; off < 64; off <<= 1) {
    int t = __shfl_up(v, off);
    if (lane >= off) v += t;
  }
  if (lane == 63) wsum[w] = v;
  __syncthreads();
  if (w == 0) {
    int s = (lane < 4) ? wsum[lane] : 0;
#pragma unroll
    for (int off = 1; off < 4; off <<= 1) {
      int t = __shfl_up(s, off);
      if (lane >= off) s += t;
    }
    if (lane < 4) wsum[lane] = s;
  }
  __syncthreads();
  const int wex = (w == 0) ? 0 : wsum[w - 1];
  if (tid < NSB2) bpre[tid] = wex + v - orig;  // exclusive
}

// cursor[i] = global exclusive prefix (scatter will bump it to inclusive).
__global__ __launch_bounds__(SCAN_BLOCK) void scan3_kernel(
    const int* __restrict__ cnt, const int* __restrict__ bpre,
    int* __restrict__ cursor) {
  const int i = blockIdx.x * SCAN_BLOCK + threadIdx.x;
  if (i < N_NODES) cursor[i] = cnt[i] + bpre[blockIdx.x];
}

// Direct atomic scatter: records land node-grouped in one pass.
// Replaces partition+place (no LDS staging, no bucket caps, no re-read).
__global__ __launch_bounds__(256) void scatter_kernel(
    const int* __restrict__ src, const int* __restrict__ dst,
    const float* __restrict__ dvec,
    const float* __restrict__ w_real, const float* __restrict__ w_imag,
    int* __restrict__ cursor, unsigned long long* __restrict__ records) {
  const int e0 = (blockIdx.x * 256 + threadIdx.x) * 4;
  if (e0 >= N_EDGES) return;  // N_EDGES % 4 == 0
  const int4 s4 = *(const int4*)(src + e0);
  const int4 t4 = *(const int4*)(dst + e0);
  const float4 wr = *(const float4*)(w_real + e0);
  const float4 wi = *(const float4*)(w_imag + e0);
#define SCAT(SS, TT, WR, WI)                                              \
  {                                                                       \
    const float ds = dvec[SS];                                            \
    const unsigned hi = pack_bf16x2(ds * (WR), ds * (WI));                \
    const int pos = atomicAdd(&cursor[TT], 1);                            \
    records[pos] = ((unsigned long long)hi << 32) | (unsigned)(SS);       \
  }
  SCAT(s4.x, t4.x, wr.x, wi.x)
  SCAT(s4.y, t4.y, wr.y, wi.y)
  SCAT(s4.z, t4.z, wr.z, wi.z)
  SCAT(s4.w, t4.w, wr.w, wi.w)
#undef SCAT
}

// Fused pull + MFMA epilogue, v4: round-1's verified branch-free inner loop,
// imbalance fixed statistically: 4 waves x 8 nodes = 32 nodes/block.
// Block time ~ max over 4 waves of Poisson(128) sums ~= 1.17x mean (vs 1.63x
// for 16 waves x 1 node). 256-thread blocks, 8.7 KB LDS -> high occupancy.
__global__ __launch_bounds__(256, 8) void pull_fused_kernel(
    const uint2* __restrict__ records, const int* __restrict__ inc,
    const float* __restrict__ dvec, const unsigned* __restrict__ hpack,
    const unsigned short* __restrict__ At, const float* __restrict__ cvec,
    float* __restrict__ zr_out, float* __restrict__ zi_out) {
  __shared__ __align__(16) unsigned short zs[32][136];  // 8.7 KB
  const int tid = threadIdx.x;
  const int lane = tid & 63;
  const int wave = tid >> 6;   // 0..3
  const int q4 = lane >> 4;    // quarter id (edge interleave)
  const int m16 = lane & 15;   // dim group: dims 4*m16 .. 4*m16+3
  const int node0 = blockIdx.x * 32;  // grid = N/32 exact
  const unsigned* __restrict__ hb = hpack + 4 * m16;

#if HAVE_DOT2
#define DOT2(acc, w_, h_)                                                   \
  acc = __builtin_amdgcn_fdot2_f32_bf16(__builtin_bit_cast(bf16x2v, (w_)),  \
                                        __builtin_bit_cast(bf16x2v, (h_)),  \
                                        acc, false)
#else
#define DOT2(acc, w_, h_)                                                   \
  {                                                                         \
    const float _wl = unpack_lo(w_), _wh = unpack_hi(w_);                   \
    const float _hl = unpack_lo(h_), _hh = unpack_hi(h_);                   \
    acc += _wl * _hl + _wh * _hh;                                           \
  }
#endif

#define ACC4(RR)                                                            \
  {                                                                         \
    const unsigned wneg = (RR).y ^ 0x80000000u;                             \
    const unsigned wswp = ((RR).y >> 16) | ((RR).y << 16);                  \
    const uint4 hv = *reinterpret_cast<const uint4*>(                       \
        hb + (size_t)(RR).x * DIM);                                         \
    DOT2(sr0, wneg, hv.x); DOT2(si0, wswp, hv.x);                           \
    DOT2(sr1, wneg, hv.y); DOT2(si1, wswp, hv.y);                           \
    DOT2(sr2, wneg, hv.z); DOT2(si2, wswp, hv.z);                           \
    DOT2(sr3, wneg, hv.w); DOT2(si3, wswp, hv.w);                           \
  }

  for (int j = 0; j < NPW; ++j) {
    const int n = node0 + wave * NPW + j;
    const int start = (n == 0) ? 0 : inc[n - 1];
    const int end = inc[n];
    const int deg = end - start;

    float sr0 = 0.f, sr1 = 0.f, sr2 = 0.f, sr3 = 0.f;
    float si0 = 0.f, si1 = 0.f, si2 = 0.f, si3 = 0.f;

    int p = start + q4;
    const int nfull = deg >> 2;
    int i = 0;
    for (; i + 2 <= nfull; i += 2) {
      const uint2 r0 = records[p];
      const uint2 r1 = records[p + 4];
      ACC4(r0);
      ACC4(r1);
      p += 8;
    }
    if (i < nfull) {
      const uint2 r0 = records[p];
      ACC4(r0);
      p += 4;
    }
    if (p < end) {
      const uint2 r0 = records[p];
      ACC4(r0);
    }

    // Merge the 4 quarter-partials (lanes L, L^16, L^32, L^48 share dims).
#define QRED(v)                  \
    v += __shfl_xor(v, 16);      \
    v += __shfl_xor(v, 32);
    QRED(sr0) QRED(sr1) QRED(sr2) QRED(sr3)
    QRED(si0) QRED(si1) QRED(si2) QRED(si3)
#undef QRED

    const float dn = dvec[n];
    if (lane < 16) {
      const int zl = wave * NPW + j;
      uint2 rv, iv;
      rv.x = pack_bf16x2(dn * sr0, dn * sr1);
      rv.y = pack_bf16x2(dn * sr2, dn * sr3);
      iv.x = pack_bf16x2(dn * si0, dn * si1);
      iv.y = pack_bf16x2(dn * si2, dn * si3);
      *reinterpret_cast<uint2*>(&zs[zl][4 * lane]) = rv;
      *reinterpret_cast<uint2*>(&zs[zl][64 + 4 * lane]) = iv;
    }
  }
#undef ACC4
#undef DOT2
  __syncthreads();

  // Epilogue: Out[node][f] = sum_k Zcat[node][k]*A_comb[k][f] + cvec[f].
  // 16 tiles (2 node-halves x 8 feature-tiles); wave t does tiles t, t+4, ...
  {
    const int m = lane & 15;
    const int q = lane >> 4;
#pragma unroll
    for (int kk = 0; kk < 4; ++kk) {
      const int tt = wave + kk * 4;  // 0..15
      const int nh = tt >> 3;        // node half
      const int ft = tt & 7;         // feature tile

      bf16x8 a[4];
#pragma unroll
      for (int c = 0; c < 4; ++c)
        a[c] = *reinterpret_cast<const bf16x8*>(&zs[nh * 16 + m][c * 32 + q * 8]);

      f32x4 acc = (f32x4){0.f, 0.f, 0.f, 0.f};
      const unsigned short* brow = At + (size_t)(ft * 16 + m) * 128 + q * 8;
#pragma unroll
      for (int c = 0; c < 4; ++c) {
        bf16x8 bfrag = *reinterpret_cast<const bf16x8*>(brow + c * 32);
        acc = __builtin_amdgcn_mfma_f32_16x16x32_bf16(a[c], bfrag, acc, 0, 0, 0);
      }

      const int nf = ft * 16 + m;
      const float bias = cvec[nf];
      float* outp = (nf < 64) ? zr_out : zi_out;
      const int nnn = nf & 63;
#pragma unroll
      for (int r = 0; r < 4; ++r) {
        const int node = node0 + nh * 16 + q * 4 + r;
        outp[(size_t)node * 64 + nnn] = acc[r] + bias;
      }
    }
  }
}

extern "C" void kernel_launch(void* const* d_in, const int* in_sizes, int n_in,
                              void* d_out, int out_size, void* d_ws, size_t ws_size,
                              hipStream_t stream) {
  const float* h_real = (const float*)d_in[0];
  const float* h_imag = (const float*)d_in[1];
  const float* dvec   = (const float*)d_in[2];
  const float* w_real = (const float*)d_in[3];
  const float* w_imag = (const float*)d_in[4];
  const int*   src    = (const int*)d_in[5];
  const int*   dst    = (const int*)d_in[6];
  const float* W1     = (const float*)d_in[7];
  const float* b1     = (const float*)d_in[8];
  const float* W2     = (const float*)d_in[9];
  const float* b2     = (const float*)d_in[10];

  char* ws = (char*)d_ws;
  unsigned short* At = (unsigned short*)ws;                          // 32 KB
  float* cvec = (float*)(ws + 128 * 128 * 2);                        // 1 KB
  unsigned long long* records = (unsigned long long*)(ws + 33792);   // 12.8 MB
  unsigned* hpack = (unsigned*)(ws + 33792 + (size_t)N_EDGES * 8);   // 25.6 MB
  int* cnt = (int*)(ws + 33792 + (size_t)N_EDGES * 8 + (size_t)N_NODES * DIM * 4);
  int* bsum = cnt + N_NODES;
  int* bpre = bsum + 128;
  int* cursor = bpre + 128;

  float* zr_out = (float*)d_out;
  float* zi_out = zr_out + (size_t)N_NODES * DIM;

  hipMemsetAsync(cnt, 0, (size_t)N_NODES * sizeof(int), stream);
  setup_fused_kernel<<<PACKB4 + 64 + HISTB, 256, 0, stream>>>(
      h_real, h_imag, (unsigned*)hpack, W1, b1, W2, b2, At, cvec, dst, cnt);
  scan1_kernel<<<NSB2, SCAN_BLOCK, 0, stream>>>(cnt, bsum);
  scan2_kernel<<<1, 256, 0, stream>>>(bsum, bpre);
  scan3_kernel<<<NSB2, SCAN_BLOCK, 0, stream>>>(cnt, bpre, cursor);
  scatter_kernel<<<HISTB, 256, 0, stream>>>(src, dst, dvec, w_real, w_imag,
                                            cursor, records);
  pull_fused_kernel<<<PULLB, 256, 0, stream>>>(
      (const uint2*)records, cursor, dvec, hpack, At, cvec, zr_out, zi_out);
}